// Round 3
// baseline (263.857 us; speedup 1.0000x reference)
//
#include <hip/hip_runtime.h>
#include <hip/hip_bf16.h>
#include <cstdint>

typedef _Float16 f16;
typedef _Float16 f16x4 __attribute__((ext_vector_type(4)));
typedef _Float16 f16x8 __attribute__((ext_vector_type(8)));
typedef float f32x4 __attribute__((ext_vector_type(4)));

#define MFMA16(a, b, c) __builtin_amdgcn_mfma_f32_16x16x32_f16((a), (b), (c), 0, 0, 0)

constexpr int BATCH = 16;
constexpr int C     = 256;    // dim
constexpr int HW    = 4096;   // 64*64 spatial
constexpr int DH    = 32;     // qkv_dim
constexpr int MR    = 288;
constexpr float EPS = 1e-5f;

// ---- workspace layout (bytes) ----
constexpr size_t OFF_P  = 0;                                   // f16 probsT [16][4096][256]
constexpr size_t SZ_P   = (size_t)BATCH * HW * C * 2;
constexpr size_t OFF_KV = OFF_P + SZ_P;                        // f32 [16][32][4096]
constexpr size_t SZ_KV  = (size_t)BATCH * DH * HW * 4;
constexpr size_t OFF_W1 = OFF_KV + SZ_KV;                      // f16 [288][256] (BN folded)
constexpr size_t SZ_W1  = (size_t)MR * C * 2;
constexpr size_t OFF_B1 = OFF_W1 + SZ_W1;                      // f32 [288]
constexpr size_t OFF_WP = OFF_B1 + 2048;                       // f16 [256][256]
constexpr size_t SZ_WP  = (size_t)C * C * 2;
constexpr size_t OFF_BP = OFF_WP + SZ_WP;                      // f32 [256]
constexpr size_t OFF_RM = OFF_BP + 1024;                       // f32 [512]
constexpr size_t OFF_RS = OFF_RM + 2048;                       // f32 [512]
constexpr size_t OFF_U  = OFF_RS + 2048;                       // f32 [16][32][32]

// ============================================================================
// K0: fold BN into conv weights; f16 weights, f32 biases
// ============================================================================
__global__ __launch_bounds__(256) void k0_prep(
    const float* __restrict__ Wq,  const float* __restrict__ gq,  const float* __restrict__ bq,
    const float* __restrict__ mq,  const float* __restrict__ vq,
    const float* __restrict__ Wkv, const float* __restrict__ gkv, const float* __restrict__ bkv,
    const float* __restrict__ mkv, const float* __restrict__ vkv,
    const float* __restrict__ Wp,  const float* __restrict__ gp,  const float* __restrict__ bp,
    const float* __restrict__ mp,  const float* __restrict__ vp,
    f16* __restrict__ W1, float* __restrict__ b1, f16* __restrict__ Wp2, float* __restrict__ bp2) {
  int id = blockIdx.x * 256 + threadIdx.x;
  if (id < 65536) {
    int o = id >> 8, c = id & 255;
    float inv = gq[o] * rsqrtf(vq[o] + EPS);
    W1[o * 256 + c] = (f16)(Wq[o * 256 + c] * inv);
  } else if (id < 73728) {
    int o = (id - 65536) >> 8, c = id & 255;
    float inv = gkv[o] * rsqrtf(vkv[o] + EPS);
    W1[(256 + o) * 256 + c] = (f16)(Wkv[o * 256 + c] * inv);
  } else if (id < 139264) {
    int o = (id - 73728) >> 8, c = id & 255;
    float inv = gp[o] * rsqrtf(vp[o] + EPS);
    Wp2[o * 256 + c] = (f16)(Wp[o * 256 + c] * inv);
  } else if (id < 139552) {
    int r = id - 139264;
    if (r < 256) { float inv = gq[r] * rsqrtf(vq[r] + EPS);   b1[r] = bq[r] - mq[r] * inv; }
    else { int e = r - 256; float inv = gkv[e] * rsqrtf(vkv[e] + EPS); b1[r] = bkv[e] - mkv[e] * inv; }
  } else if (id < 139808) {
    int o = id - 139552;
    float inv = gp[o] * rsqrtf(vp[o] + EPS);
    bp2[o] = bp[o] - mp[o] * inv;
  }
}

// ============================================================================
// K1: QKV GEMM + per-head channel softmax of q + transposed probs output.
//   D(288x64tile) = W1(288x256) * X(256x64tile), bias in acc-init.
//   X staged in 2 half-K phases (LDS fp32 [128][pitch65]); K-loop vmem = af only.
//   q rows -> softmax over e (quad shuffles) -> probsT[n][o] f16 via LDS bounce.
//   kv rows (mf==8) -> fp32 [d][n].
// Wave map: wn = w&1 (n-half), wm = w>>1 (m-half: q rows wm*128+, kv rows wm*16+).
// ============================================================================
__global__ __launch_bounds__(256, 4) void k1_qkv(
    const float* __restrict__ X, const f16* __restrict__ W1, const float* __restrict__ b1,
    f16* __restrict__ probsT, float* __restrict__ kvo) {
  __shared__ alignas(16) char smem_raw[64 * 264 * 2];  // 33792 B: xt fp32[128][65] (33280) | pb f16[64][264]
  float* xt = (float*)smem_raw;
  f16*   pb = (f16*)smem_raw;

  const int t  = threadIdx.x;
  const int n0 = blockIdx.x * 64;
  const int b  = blockIdx.y;
  const float* Xb = X + (size_t)b * C * HW;

  const int lane = t & 63, w = t >> 6;
  const int l15 = lane & 15, quad = lane >> 4;
  const int wn = w & 1, wm = w >> 1;

  // acc init = bias (folds BN shift; softmax needs bias included anyway)
  f32x4 acc[9][2];
#pragma unroll
  for (int mf = 0; mf < 9; ++mf) {
#pragma unroll
    for (int r = 0; r < 4; ++r) {
      int o = (mf < 8) ? (wm * 128 + mf * 16 + quad * 4 + r) : (256 + wm * 16 + quad * 4 + r);
      float bv = b1[o];
      acc[mf][0][r] = bv; acc[mf][1][r] = bv;
    }
  }

  for (int half = 0; half < 2; ++half) {
    if (half) __syncthreads();  // all waves done reading previous xt
    // stage X[half*128 .. +127][n0 .. n0+63] -> xt, 8 independent float4/thread
    {
      int n4 = (t & 15) * 4, c0 = t >> 4;
      const float* Xp = Xb + (size_t)(half * 128 + c0) * HW + n0 + n4;
      float4 v[8];
#pragma unroll
      for (int i = 0; i < 8; ++i) v[i] = *(const float4*)&Xp[(size_t)i * 16 * HW];
#pragma unroll
      for (int i = 0; i < 8; ++i) *(float4*)&xt[(c0 + i * 16) * 65 + n4] = v[i];
    }
    __syncthreads();

    for (int kcl = 0; kcl < 4; ++kcl) {
      int kc = half * 4 + kcl;
      // build B fragments from LDS (fp32 -> f16)
      f16x8 bf0, bf1;
#pragma unroll
      for (int j = 0; j < 8; ++j) {
        int row = (kcl * 32 + quad * 8 + j) * 65;
        bf0[j] = (f16)xt[row + wn * 32 + l15];
        bf1[j] = (f16)xt[row + wn * 32 + 16 + l15];
      }
#pragma unroll
      for (int mf = 0; mf < 9; ++mf) {
        int row = (mf < 8) ? (wm * 128 + mf * 16 + l15) : (256 + wm * 16 + l15);
        f16x8 af = *(const f16x8*)&W1[row * 256 + kc * 32 + quad * 8];
        acc[mf][0] = MFMA16(af, bf0, acc[mf][0]);
        acc[mf][1] = MFMA16(af, bf1, acc[mf][1]);
      }
    }
  }
  __syncthreads();  // xt dead; pb region takes over

  // ---- q softmax over e within head (heads wm*4 + j), probs -> pb[n][o] ----
#pragma unroll
  for (int j = 0; j < 4; ++j) {
#pragma unroll
    for (int nf = 0; nf < 2; ++nf) {
      float m = -1e30f;
#pragma unroll
      for (int mh = 0; mh < 2; ++mh)
#pragma unroll
        for (int r = 0; r < 4; ++r) m = fmaxf(m, acc[j * 2 + mh][nf][r]);
      m = fmaxf(m, __shfl_xor(m, 16));
      m = fmaxf(m, __shfl_xor(m, 32));
      float p[2][4]; float s = 0.f;
#pragma unroll
      for (int mh = 0; mh < 2; ++mh)
#pragma unroll
        for (int r = 0; r < 4; ++r) { p[mh][r] = __expf(acc[j * 2 + mh][nf][r] - m); s += p[mh][r]; }
      s += __shfl_xor(s, 16);
      s += __shfl_xor(s, 32);
      float sinv = 1.f / s;
      int n = wn * 32 + nf * 16 + l15;
#pragma unroll
      for (int mh = 0; mh < 2; ++mh) {
        int o = wm * 128 + (j * 2 + mh) * 16 + quad * 4;
        f16x4 pk = { (f16)(p[mh][0] * sinv), (f16)(p[mh][1] * sinv),
                     (f16)(p[mh][2] * sinv), (f16)(p[mh][3] * sinv) };
        *(f16x4*)&pb[n * 264 + o] = pk;
      }
    }
  }
  // ---- kv rows direct to global fp32 ----
#pragma unroll
  for (int nf = 0; nf < 2; ++nf) {
    int n = n0 + wn * 32 + nf * 16 + l15;
#pragma unroll
    for (int r = 0; r < 4; ++r) {
      int d = wm * 16 + quad * 4 + r;
      kvo[((size_t)b * DH + d) * HW + n] = acc[8][nf][r];
    }
  }
  __syncthreads();
  // ---- pb -> probsT coalesced (64 rows x 512 B) ----
#pragma unroll
  for (int i = 0; i < 8; ++i) {
    int id = t + i * 256;
    int n = id >> 5, s2 = id & 31;
    f16x8 v = *(const f16x8*)&pb[n * 264 + s2 * 8];
    *(f16x8*)&probsT[((size_t)b * HW + n0 + n) * 256 + s2 * 8] = v;
  }
}

// ============================================================================
// K2: per-kv-row softmax stats; row in registers, single pass.
// ============================================================================
__global__ __launch_bounds__(256) void k2_stats(
    const float* __restrict__ kv, float* __restrict__ rowmax, float* __restrict__ rowsum) {
  int r = blockIdx.x, t = threadIdx.x, w = t >> 6, lane = t & 63;
  const float4* row = (const float4*)(kv + (size_t)r * HW);
  float4 v0 = row[t], v1 = row[t + 256], v2 = row[t + 512], v3 = row[t + 768];
  float m = fmaxf(fmaxf(fmaxf(v0.x, v0.y), fmaxf(v0.z, v0.w)),
                  fmaxf(fmaxf(v1.x, v1.y), fmaxf(v1.z, v1.w)));
  m = fmaxf(m, fmaxf(fmaxf(fmaxf(v2.x, v2.y), fmaxf(v2.z, v2.w)),
                     fmaxf(fmaxf(v3.x, v3.y), fmaxf(v3.z, v3.w))));
  for (int off = 32; off; off >>= 1) m = fmaxf(m, __shfl_xor(m, off));
  __shared__ float sm[4], ss[4];
  if (lane == 0) sm[w] = m;
  __syncthreads();
  m = fmaxf(fmaxf(sm[0], sm[1]), fmaxf(sm[2], sm[3]));
  float s = __expf(v0.x - m) + __expf(v0.y - m) + __expf(v0.z - m) + __expf(v0.w - m)
          + __expf(v1.x - m) + __expf(v1.y - m) + __expf(v1.z - m) + __expf(v1.w - m)
          + __expf(v2.x - m) + __expf(v2.y - m) + __expf(v2.z - m) + __expf(v2.w - m)
          + __expf(v3.x - m) + __expf(v3.y - m) + __expf(v3.z - m) + __expf(v3.w - m);
  for (int off = 32; off; off >>= 1) s += __shfl_xor(s, off);
  if (lane == 0) ss[w] = s;
  __syncthreads();
  if (t == 0) { rowmax[r] = m; rowsum[r] = ss[0] + ss[1] + ss[2] + ss[3]; }
}

// ============================================================================
// K3: ctx_t[b][d][e] = sum_n softmaxrow_e(kv)[n] * kv[d][n]  (1/S_e folded)
// ============================================================================
__global__ __launch_bounds__(256) void k3_ctx(
    const float* __restrict__ kv, const float* __restrict__ rowmax,
    const float* __restrict__ rowsum, float* __restrict__ U) {
  __shared__ alignas(16) float kvc[256 * 36];
  __shared__ alignas(16) float wc [256 * 36];

  const int t = threadIdx.x;
  const int b = blockIdx.y;
  const int n0 = blockIdx.x * 256;

  for (int idx = t; idx < 32 * 64; idx += 256) {
    int r = idx & 31, nq = idx >> 5;
    const float4 v = *(const float4*)&kv[((size_t)b * DH + r) * HW + n0 + nq * 4];
    float M = rowmax[b * DH + r];
    float Sinv = 1.f / rowsum[b * DH + r];
    int n = nq * 4;
    kvc[(n + 0) * 36 + r] = v.x;  wc[(n + 0) * 36 + r] = __expf(v.x - M) * Sinv;
    kvc[(n + 1) * 36 + r] = v.y;  wc[(n + 1) * 36 + r] = __expf(v.y - M) * Sinv;
    kvc[(n + 2) * 36 + r] = v.z;  wc[(n + 2) * 36 + r] = __expf(v.z - M) * Sinv;
    kvc[(n + 3) * 36 + r] = v.w;  wc[(n + 3) * 36 + r] = __expf(v.w - M) * Sinv;
  }
  __syncthreads();

  const int d = t & 31, eg = t >> 5;
  float a0 = 0, a1 = 0, a2 = 0, a3 = 0;
  for (int n = 0; n < 256; ++n) {
    float kd = kvc[n * 36 + d];
    const float4 w4 = *(const float4*)&wc[n * 36 + eg * 4];
    a0 += w4.x * kd; a1 += w4.y * kd; a2 += w4.z * kd; a3 += w4.w * kd;
  }
  float* Ub = U + b * 1024 + d * 32 + eg * 4;
  atomicAdd(Ub + 0, a0); atomicAdd(Ub + 1, a1);
  atomicAdd(Ub + 2, a2); atomicAdd(Ub + 3, a3);
}

// ============================================================================
// K4: attended = ctx_t * probs (MFMA, probsT fragments straight from global),
//     ReLU -> att_t LDS, then proj GEMM (af from L2-hot Wp2, bias in acc-init).
// ============================================================================
__global__ __launch_bounds__(256, 4) void k4_attproj(
    const f16* __restrict__ probsT, const float* __restrict__ U,
    const f16* __restrict__ Wp2, const float* __restrict__ bp2, float* __restrict__ out) {
  __shared__ alignas(16) f16 att[64 * 264];   // probs-free; att_t[n][c] pitch 264
  __shared__ alignas(16) f16 ctxs[32 * 32];   // ctx_t [d][e]

  const int t = threadIdx.x;
  const int b = blockIdx.y;
  const int n0 = blockIdx.x * 64;
  const int lane = t & 63, w = t >> 6;
  const int l15 = lane & 15, quad = lane >> 4;

  {
    const float4 u4 = *(const float4*)&U[b * 1024 + t * 4];
    f16x4 pk = { (f16)u4.x, (f16)u4.y, (f16)u4.z, (f16)u4.w };
    *(f16x4*)&ctxs[t * 4] = pk;
  }
  __syncthreads();

  // attended: wave w -> heads 2w, 2w+1. B-fragments from global probsT.
  const f16* pT = probsT + (size_t)b * HW * 256;
  f32x4 attacc[2][2][4] = {};
#pragma unroll
  for (int hh = 0; hh < 2; ++hh) {
    int h = w * 2 + hh;
#pragma unroll
    for (int nt = 0; nt < 4; ++nt) {
      f16x8 bf = *(const f16x8*)&pT[(size_t)(n0 + nt * 16 + l15) * 256 + h * 32 + quad * 8];
#pragma unroll
      for (int mt = 0; mt < 2; ++mt) {
        f16x8 af = *(const f16x8*)&ctxs[(mt * 16 + l15) * 32 + quad * 8];
        attacc[hh][mt][nt] = MFMA16(af, bf, attacc[hh][mt][nt]);
      }
    }
  }
  // ReLU -> att_t (each wave writes only its own heads' columns)
#pragma unroll
  for (int hh = 0; hh < 2; ++hh) {
#pragma unroll
    for (int mt = 0; mt < 2; ++mt) {
#pragma unroll
      for (int nt = 0; nt < 4; ++nt) {
        int n = nt * 16 + l15;
        int cb = (w * 2 + hh) * 32 + mt * 16 + quad * 4;
        f32x4 v = attacc[hh][mt][nt];
        f16x4 pk = { (f16)fmaxf(v[0], 0.f), (f16)fmaxf(v[1], 0.f),
                     (f16)fmaxf(v[2], 0.f), (f16)fmaxf(v[3], 0.f) };
        *(f16x4*)&att[n * 264 + cb] = pk;
      }
    }
  }
  __syncthreads();

  // proj GEMM: waves 2x2 (wm: M-half 128, wn: N-half 32); bias in acc-init
  const int wm = w & 1, wn = w >> 1;
  f32x4 acc[8][2];
#pragma unroll
  for (int mf = 0; mf < 8; ++mf)
#pragma unroll
    for (int r = 0; r < 4; ++r) {
      float bv = bp2[wm * 128 + mf * 16 + quad * 4 + r];
      acc[mf][0][r] = bv; acc[mf][1][r] = bv;
    }
#pragma unroll
  for (int kc = 0; kc < 8; ++kc) {
    f16x8 bf0 = *(const f16x8*)&att[(wn * 32 + l15) * 264 + kc * 32 + quad * 8];
    f16x8 bf1 = *(const f16x8*)&att[(wn * 32 + 16 + l15) * 264 + kc * 32 + quad * 8];
#pragma unroll
    for (int mf = 0; mf < 8; ++mf) {
      f16x8 af = *(const f16x8*)&Wp2[(wm * 128 + mf * 16 + l15) * 256 + kc * 32 + quad * 8];
      acc[mf][0] = MFMA16(af, bf0, acc[mf][0]);
      acc[mf][1] = MFMA16(af, bf1, acc[mf][1]);
    }
  }
#pragma unroll
  for (int mf = 0; mf < 8; ++mf) {
#pragma unroll
    for (int nf = 0; nf < 2; ++nf) {
      int n = n0 + wn * 32 + nf * 16 + l15;
#pragma unroll
      for (int r = 0; r < 4; ++r) {
        int o = wm * 128 + mf * 16 + quad * 4 + r;
        out[((size_t)b * C + o) * HW + n] = acc[mf][nf][r];
      }
    }
  }
}

// ============================================================================
extern "C" void kernel_launch(void* const* d_in, const int* in_sizes, int n_in,
                              void* d_out, int out_size, void* d_ws, size_t ws_size,
                              hipStream_t stream) {
  (void)in_sizes; (void)n_in; (void)out_size; (void)ws_size;
  const float* input = (const float*)d_in[0];
  const float* Wq  = (const float*)d_in[2];
  const float* gq  = (const float*)d_in[3];
  const float* bq  = (const float*)d_in[4];
  const float* mq  = (const float*)d_in[5];
  const float* vq  = (const float*)d_in[6];
  const float* Wkv = (const float*)d_in[7];
  const float* gkv = (const float*)d_in[8];
  const float* bkv = (const float*)d_in[9];
  const float* mkv = (const float*)d_in[10];
  const float* vkv = (const float*)d_in[11];
  const float* Wp  = (const float*)d_in[12];
  const float* gp  = (const float*)d_in[13];
  const float* bp  = (const float*)d_in[14];
  const float* mp  = (const float*)d_in[15];
  const float* vp  = (const float*)d_in[16];

  char* ws = (char*)d_ws;
  f16*   pT  = (f16*)(ws + OFF_P);
  float* kvw = (float*)(ws + OFF_KV);
  f16*   W1  = (f16*)(ws + OFF_W1);
  float* b1  = (float*)(ws + OFF_B1);
  f16*   Wp2 = (f16*)(ws + OFF_WP);
  float* bp2 = (float*)(ws + OFF_BP);
  float* rm  = (float*)(ws + OFF_RM);
  float* rs  = (float*)(ws + OFF_RS);
  float* U   = (float*)(ws + OFF_U);
  float* out = (float*)d_out;

  hipMemsetAsync(U, 0, (size_t)BATCH * DH * DH * 4, stream);
  k0_prep<<<547, 256, 0, stream>>>(Wq, gq, bq, mq, vq, Wkv, gkv, bkv, mkv, vkv,
                                   Wp, gp, bp, mp, vp, W1, b1, Wp2, bp2);
  k1_qkv<<<dim3(64, 16), 256, 0, stream>>>(input, W1, b1, pT, kvw);
  k2_stats<<<512, 256, 0, stream>>>(kvw, rm, rs);
  k3_ctx<<<dim3(16, 16), 256, 0, stream>>>(kvw, rm, rs, U);
  k4_attproj<<<dim3(64, 16), 256, 0, stream>>>(pT, U, Wp2, bp2, out);
}

// Round 4
// 224.712 us; speedup vs baseline: 1.1742x; 1.1742x over previous
//
#include <hip/hip_runtime.h>
#include <hip/hip_bf16.h>
#include <cstdint>

typedef _Float16 f16;
typedef _Float16 f16x4 __attribute__((ext_vector_type(4)));
typedef _Float16 f16x8 __attribute__((ext_vector_type(8)));
typedef float f32x4 __attribute__((ext_vector_type(4)));

#define MFMA16(a, b, c) __builtin_amdgcn_mfma_f32_16x16x32_f16((a), (b), (c), 0, 0, 0)

constexpr int BATCH = 16;
constexpr int C     = 256;    // dim
constexpr int HW    = 4096;   // 64*64 spatial
constexpr int DH    = 32;     // qkv_dim
constexpr int MR    = 288;
constexpr float EPS = 1e-5f;

// ---- workspace layout (bytes) ----
constexpr size_t OFF_XT = 0;                                   // f16 XT [16][4096][256]
constexpr size_t SZ_XT  = (size_t)BATCH * HW * C * 2;
constexpr size_t OFF_KV = OFF_XT + SZ_XT;                      // f32 [16*32][4096]
constexpr size_t SZ_KV  = (size_t)BATCH * DH * HW * 4;
constexpr size_t OFF_W1 = OFF_KV + SZ_KV;                      // f16 [288][256] (BN folded; rows 0..255 = Wq', 256..287 = Wkv')
constexpr size_t SZ_W1  = (size_t)MR * C * 2;
constexpr size_t OFF_B1 = OFF_W1 + SZ_W1;                      // f32 [288]
constexpr size_t OFF_WP = OFF_B1 + 2048;                       // f16 [256][256]
constexpr size_t SZ_WP  = (size_t)C * C * 2;
constexpr size_t OFF_BP = OFF_WP + SZ_WP;                      // f32 [256]
constexpr size_t OFF_RM = OFF_BP + 1024;                       // f32 [512]
constexpr size_t OFF_RS = OFF_RM + 2048;                       // f32 [512]
constexpr size_t OFF_U  = OFF_RS + 2048;                       // f32 [16][32][32]

// ============================================================================
// K0: fold BN into conv weights; f16 weights, f32 biases
// ============================================================================
__global__ __launch_bounds__(256) void k0_prep(
    const float* __restrict__ Wq,  const float* __restrict__ gq,  const float* __restrict__ bq,
    const float* __restrict__ mq,  const float* __restrict__ vq,
    const float* __restrict__ Wkv, const float* __restrict__ gkv, const float* __restrict__ bkv,
    const float* __restrict__ mkv, const float* __restrict__ vkv,
    const float* __restrict__ Wp,  const float* __restrict__ gp,  const float* __restrict__ bp,
    const float* __restrict__ mp,  const float* __restrict__ vp,
    f16* __restrict__ W1, float* __restrict__ b1, f16* __restrict__ Wp2, float* __restrict__ bp2) {
  int id = blockIdx.x * 256 + threadIdx.x;
  if (id < 65536) {
    int o = id >> 8, c = id & 255;
    float inv = gq[o] * rsqrtf(vq[o] + EPS);
    W1[o * 256 + c] = (f16)(Wq[o * 256 + c] * inv);
  } else if (id < 73728) {
    int o = (id - 65536) >> 8, c = id & 255;
    float inv = gkv[o] * rsqrtf(vkv[o] + EPS);
    W1[(256 + o) * 256 + c] = (f16)(Wkv[o * 256 + c] * inv);
  } else if (id < 139264) {
    int o = (id - 73728) >> 8, c = id & 255;
    float inv = gp[o] * rsqrtf(vp[o] + EPS);
    Wp2[o * 256 + c] = (f16)(Wp[o * 256 + c] * inv);
  } else if (id < 139552) {
    int r = id - 139264;
    if (r < 256) { float inv = gq[r] * rsqrtf(vq[r] + EPS);   b1[r] = bq[r] - mq[r] * inv; }
    else { int e = r - 256; float inv = gkv[e] * rsqrtf(vkv[e] + EPS); b1[r] = bkv[e] - mkv[e] * inv; }
  } else if (id < 139808) {
    int o = id - 139552;
    float inv = gp[o] * rsqrtf(vp[o] + EPS);
    bp2[o] = bp[o] - mp[o] * inv;
  }
}

// ============================================================================
// P0: transpose+cvt X[b][c][n] f32 -> XT[b][n][c] f16 (4x4 register transpose
// through LDS, all vectorized), AND compute kv[b*32+d][n] fp32 via MFMA
// (block holds full K=256 in LDS, so kv is exact — no partials/atomics).
// ============================================================================
__global__ __launch_bounds__(256, 3) void p0_trans_kv(
    const float* __restrict__ X, const f16* __restrict__ Wkv2, const float* __restrict__ bkv1,
    f16* __restrict__ XT, float* __restrict__ kvo) {
  __shared__ alignas(16) f16 xt[64 * 264];     // [n][c] pitch 264
  __shared__ alignas(16) float kvb[32 * 68];   // bounce [d][n] pitch 68
  const int t = threadIdx.x, b = blockIdx.y, n0 = blockIdx.x * 64;
  const int lane = t & 63, w = t >> 6, l15 = lane & 15, quad = lane >> 4;
  const float* Xb = X + (size_t)b * C * HW;

  // phase 1: 4x4 register transpose f32->f16 into [n][c] LDS
  {
    int c4 = (t & 15) * 4, n4 = (t >> 4) * 4;
#pragma unroll
    for (int ci = 0; ci < 4; ++ci) {
      int c0 = ci * 64 + c4;
      const float* xp = Xb + (size_t)c0 * HW + n0 + n4;
      float4 v0 = *(const float4*)&xp[0];
      float4 v1 = *(const float4*)&xp[HW];
      float4 v2 = *(const float4*)&xp[2 * HW];
      float4 v3 = *(const float4*)&xp[3 * HW];
      f16x4 w0 = {(f16)v0.x, (f16)v1.x, (f16)v2.x, (f16)v3.x};
      f16x4 w1 = {(f16)v0.y, (f16)v1.y, (f16)v2.y, (f16)v3.y};
      f16x4 w2 = {(f16)v0.z, (f16)v1.z, (f16)v2.z, (f16)v3.z};
      f16x4 w3 = {(f16)v0.w, (f16)v1.w, (f16)v2.w, (f16)v3.w};
      *(f16x4*)&xt[(n4 + 0) * 264 + c0] = w0;
      *(f16x4*)&xt[(n4 + 1) * 264 + c0] = w1;
      *(f16x4*)&xt[(n4 + 2) * 264 + c0] = w2;
      *(f16x4*)&xt[(n4 + 3) * 264 + c0] = w3;
    }
  }
  __syncthreads();

  // phase 2a: coalesced XT stores (512 B per row)
#pragma unroll
  for (int i = 0; i < 8; ++i) {
    int u = t + i * 256, row = u >> 5, seg = u & 31;
    f16x8 v = *(const f16x8*)&xt[row * 264 + seg * 8];
    *(f16x8*)&XT[((size_t)b * HW + n0 + row) * 256 + seg * 8] = v;
  }

  // phase 2b: kv GEMM. D[n][d]: A = xt[n][c] (wave w owns n rows w*16..+15),
  // B-frags from L2-hot Wkv2 (32x256). Bias in acc init.
  f32x4 acc0, acc1;
  {
    float bv0 = bkv1[l15], bv1 = bkv1[16 + l15];
#pragma unroll
    for (int r = 0; r < 4; ++r) { acc0[r] = bv0; acc1[r] = bv1; }
  }
#pragma unroll
  for (int kc = 0; kc < 8; ++kc) {
    f16x8 af  = *(const f16x8*)&xt[(w * 16 + l15) * 264 + kc * 32 + quad * 8];
    f16x8 bf0 = *(const f16x8*)&Wkv2[l15 * 256 + kc * 32 + quad * 8];
    f16x8 bf1 = *(const f16x8*)&Wkv2[(16 + l15) * 256 + kc * 32 + quad * 8];
    acc0 = MFMA16(af, bf0, acc0);
    acc1 = MFMA16(af, bf1, acc1);
  }
  // bounce to [d][n] then coalesced stores
#pragma unroll
  for (int r = 0; r < 4; ++r) {
    int n = w * 16 + quad * 4 + r;
    kvb[l15 * 68 + n] = acc0[r];
    kvb[(16 + l15) * 68 + n] = acc1[r];
  }
  __syncthreads();
#pragma unroll
  for (int i = 0; i < 2; ++i) {
    int u = t + i * 256, d = u >> 4, seg = u & 15;
    float4 v = *(const float4*)&kvb[d * 68 + seg * 4];
    *(float4*)&kvo[((size_t)b * DH + d) * HW + n0 + seg * 4] = v;
  }
}

// ============================================================================
// K2: per-kv-row softmax stats; row in registers, single pass.
// ============================================================================
__global__ __launch_bounds__(256) void k2_stats(
    const float* __restrict__ kv, float* __restrict__ rowmax, float* __restrict__ rowsum) {
  int r = blockIdx.x, t = threadIdx.x, w = t >> 6, lane = t & 63;
  const float4* row = (const float4*)(kv + (size_t)r * HW);
  float4 v0 = row[t], v1 = row[t + 256], v2 = row[t + 512], v3 = row[t + 768];
  float m = fmaxf(fmaxf(fmaxf(v0.x, v0.y), fmaxf(v0.z, v0.w)),
                  fmaxf(fmaxf(v1.x, v1.y), fmaxf(v1.z, v1.w)));
  m = fmaxf(m, fmaxf(fmaxf(fmaxf(v2.x, v2.y), fmaxf(v2.z, v2.w)),
                     fmaxf(fmaxf(v3.x, v3.y), fmaxf(v3.z, v3.w))));
  for (int off = 32; off; off >>= 1) m = fmaxf(m, __shfl_xor(m, off));
  __shared__ float sm[4], ss[4];
  if (lane == 0) sm[w] = m;
  __syncthreads();
  m = fmaxf(fmaxf(sm[0], sm[1]), fmaxf(sm[2], sm[3]));
  float s = __expf(v0.x - m) + __expf(v0.y - m) + __expf(v0.z - m) + __expf(v0.w - m)
          + __expf(v1.x - m) + __expf(v1.y - m) + __expf(v1.z - m) + __expf(v1.w - m)
          + __expf(v2.x - m) + __expf(v2.y - m) + __expf(v2.z - m) + __expf(v2.w - m)
          + __expf(v3.x - m) + __expf(v3.y - m) + __expf(v3.z - m) + __expf(v3.w - m);
  for (int off = 32; off; off >>= 1) s += __shfl_xor(s, off);
  if (lane == 0) ss[w] = s;
  __syncthreads();
  if (t == 0) { rowmax[r] = m; rowsum[r] = ss[0] + ss[1] + ss[2] + ss[3]; }
}

// ============================================================================
// K3: ctx_t[b][d][e] = sum_n kv[d][n] * softmaxrow_e(kv)[n] via MFMA.
// A-frag = kv rows (f16), B-frag = exp of the SAME loaded values (rows as e).
// LDS reduce across waves, then one global atomicAdd per element.
// ============================================================================
__global__ __launch_bounds__(256, 4) void k3_ctx(
    const float* __restrict__ kv, const float* __restrict__ rowmax,
    const float* __restrict__ rowsum, float* __restrict__ U) {
  __shared__ float cacc[32 * 33];
  const int t = threadIdx.x, b = blockIdx.y;
  const int lane = t & 63, w = t >> 6, l15 = lane & 15, quad = lane >> 4;
  for (int i = t; i < 32 * 33; i += 256) cacc[i] = 0.f;
  __syncthreads();
  const float* kvb = kv + (size_t)b * DH * HW;
  float M0 = rowmax[b * 32 + l15],      Si0 = 1.f / rowsum[b * 32 + l15];
  float M1 = rowmax[b * 32 + 16 + l15], Si1 = 1.f / rowsum[b * 32 + 16 + l15];
  f32x4 acc[2][2] = {};
#pragma unroll
  for (int s = 0; s < 4; ++s) {
    int nb = blockIdx.x * 512 + w * 128 + s * 32 + quad * 8;
    const float* p0 = &kvb[(size_t)l15 * HW + nb];
    const float* p1 = &kvb[(size_t)(16 + l15) * HW + nb];
    float lo[8], hi[8];
    *(float4*)&lo[0] = *(const float4*)&p0[0]; *(float4*)&lo[4] = *(const float4*)&p0[4];
    *(float4*)&hi[0] = *(const float4*)&p1[0]; *(float4*)&hi[4] = *(const float4*)&p1[4];
    f16x8 A0, A1, B0, B1;
#pragma unroll
    for (int j = 0; j < 8; ++j) {
      A0[j] = (f16)lo[j]; A1[j] = (f16)hi[j];
      B0[j] = (f16)(__expf(lo[j] - M0) * Si0);
      B1[j] = (f16)(__expf(hi[j] - M1) * Si1);
    }
    acc[0][0] = MFMA16(A0, B0, acc[0][0]);
    acc[1][0] = MFMA16(A1, B0, acc[1][0]);
    acc[0][1] = MFMA16(A0, B1, acc[0][1]);
    acc[1][1] = MFMA16(A1, B1, acc[1][1]);
  }
#pragma unroll
  for (int a = 0; a < 2; ++a)
#pragma unroll
    for (int e2 = 0; e2 < 2; ++e2)
#pragma unroll
      for (int r = 0; r < 4; ++r)
        atomicAdd(&cacc[(a * 16 + quad * 4 + r) * 33 + e2 * 16 + l15], acc[a][e2][r]);
  __syncthreads();
  for (int i = t; i < 1024; i += 256)
    atomicAdd(&U[b * 1024 + (i >> 5) * 32 + (i & 31)], cacc[(i >> 5) * 33 + (i & 31)]);
}

// ============================================================================
// KB: mega-kernel per 64-position tile:
//   GEMM1 q = Wq'.X (staged LDS tiles, b128 frags) -> in-register softmax ->
//   probs LDS -> attended = ctx_t.probs (MFMA) -> ReLU in-place -> GEMM2 proj
//   (staged Wp') -> out. probsT global intermediate eliminated.
// ============================================================================
__global__ __launch_bounds__(256, 2) void kb_mega(
    const f16* __restrict__ XT, const f16* __restrict__ Wq2, const float* __restrict__ bq1,
    const float* __restrict__ U, const f16* __restrict__ Wp2, const float* __restrict__ bp1,
    float* __restrict__ out) {
  __shared__ alignas(16) f16 xs[64 * 40];      // XT tile [n][32k] pitch 40
  __shared__ alignas(16) f16 wsv[256 * 40];    // W tile  [o][32k] pitch 40
  __shared__ alignas(16) f16 pa[64 * 264];     // probs / att [n][o|c] pitch 264
  __shared__ alignas(16) f16 ctxs[32 * 40];    // ctx_t [d][e] pitch 40
  const int t = threadIdx.x, b = blockIdx.y, n0 = blockIdx.x * 64;
  const int lane = t & 63, w = t >> 6, l15 = lane & 15, quad = lane >> 4;
  const int wn = w & 1, wm = w >> 1;   // GEMM1: wn = o-half(128), wm = n-half(32)

  // stage ctx (f32 -> f16, e-contiguous rows)
  {
    const float4 u4 = *(const float4*)&U[b * 1024 + t * 4];
    int d = t >> 3, e4 = (t & 7) * 4;
    f16x4 pk = {(f16)u4.x, (f16)u4.y, (f16)u4.z, (f16)u4.w};
    *(f16x4*)&ctxs[d * 40 + e4] = pk;
  }
  const f16* XTb = XT + ((size_t)b * HW + n0) * 256;
  const int sr = t >> 2, ss = t & 3;   // staging (row, 16B-seg)

  // ---------------- GEMM1: D1[n 64][o 256] ----------------
  f32x4 acc1[2][8];
#pragma unroll
  for (int nf = 0; nf < 8; ++nf) {
    float bv = bq1[wn * 128 + nf * 16 + l15];
#pragma unroll
    for (int mf = 0; mf < 2; ++mf)
#pragma unroll
      for (int r = 0; r < 4; ++r) acc1[mf][nf][r] = bv;
  }
#pragma unroll 1
  for (int kc = 0; kc < 8; ++kc) {
    f16x8 vx, vw[4];
    vx = *(const f16x8*)&XTb[(size_t)sr * 256 + kc * 32 + ss * 8];
#pragma unroll
    for (int i = 0; i < 4; ++i)
      vw[i] = *(const f16x8*)&Wq2[(size_t)(sr + i * 64) * 256 + kc * 32 + ss * 8];
    __syncthreads();                       // prior iter's frag reads done
    *(f16x8*)&xs[sr * 40 + ss * 8] = vx;
#pragma unroll
    for (int i = 0; i < 4; ++i) *(f16x8*)&wsv[(sr + i * 64) * 40 + ss * 8] = vw[i];
    __syncthreads();
    f16x8 a0 = *(const f16x8*)&xs[(wm * 32 + l15) * 40 + quad * 8];
    f16x8 a1 = *(const f16x8*)&xs[(wm * 32 + 16 + l15) * 40 + quad * 8];
#pragma unroll
    for (int nf = 0; nf < 8; ++nf) {
      f16x8 bf = *(const f16x8*)&wsv[(wn * 128 + nf * 16 + l15) * 40 + quad * 8];
      acc1[0][nf] = MFMA16(a0, bf, acc1[0][nf]);
      acc1[1][nf] = MFMA16(a1, bf, acc1[1][nf]);
    }
  }

  // ---------------- softmax over e per head (in-wave, l15 shuffles) --------
#pragma unroll
  for (int mf = 0; mf < 2; ++mf)
#pragma unroll
    for (int h = 0; h < 4; ++h) {
      f32x4 v0 = acc1[mf][h * 2], v1 = acc1[mf][h * 2 + 1];
      f32x4 mx;
#pragma unroll
      for (int r = 0; r < 4; ++r) mx[r] = fmaxf(v0[r], v1[r]);
#pragma unroll
      for (int off = 1; off <= 8; off <<= 1)
#pragma unroll
        for (int r = 0; r < 4; ++r) mx[r] = fmaxf(mx[r], __shfl_xor(mx[r], off));
      f32x4 s4;
#pragma unroll
      for (int r = 0; r < 4; ++r) {
        v0[r] = __expf(v0[r] - mx[r]); v1[r] = __expf(v1[r] - mx[r]);
        s4[r] = v0[r] + v1[r];
      }
#pragma unroll
      for (int off = 1; off <= 8; off <<= 1)
#pragma unroll
        for (int r = 0; r < 4; ++r) s4[r] += __shfl_xor(s4[r], off);
      int o0 = wn * 128 + h * 32 + l15;
#pragma unroll
      for (int r = 0; r < 4; ++r) {
        int n = wm * 32 + mf * 16 + quad * 4 + r;
        float si = 1.f / s4[r];
        pa[n * 264 + o0]      = (f16)(v0[r] * si);
        pa[n * 264 + o0 + 16] = (f16)(v1[r] * si);
      }
    }
  __syncthreads();

  // ---------------- attended = ctx_t * probs per head; ReLU in-place -------
  f32x4 datt[2][2][4] = {};   // [head-local][d-half][n-frag]
#pragma unroll
  for (int hh = 0; hh < 2; ++hh) {
    int h = w * 2 + hh;
#pragma unroll
    for (int mt = 0; mt < 2; ++mt) {
      f16x8 af = *(const f16x8*)&ctxs[(mt * 16 + l15) * 40 + quad * 8];
#pragma unroll
      for (int nt = 0; nt < 4; ++nt) {
        f16x8 bf = *(const f16x8*)&pa[(nt * 16 + l15) * 264 + h * 32 + quad * 8];
        datt[hh][mt][nt] = MFMA16(af, bf, datt[hh][mt][nt]);
      }
    }
  }
#pragma unroll
  for (int hh = 0; hh < 2; ++hh) {
    int h = w * 2 + hh;
#pragma unroll
    for (int mt = 0; mt < 2; ++mt)
#pragma unroll
      for (int nt = 0; nt < 4; ++nt)
#pragma unroll
        for (int r = 0; r < 4; ++r) {
          int n = nt * 16 + l15;
          int cc = h * 32 + mt * 16 + quad * 4 + r;
          pa[n * 264 + cc] = (f16)fmaxf(datt[hh][mt][nt][r], 0.f);
        }
  }
  __syncthreads();

  // ---------------- GEMM2: out[o2 256][n 64] = Wp'.att^T + bias ------------
  f32x4 acc2[8][2];
#pragma unroll
  for (int mf = 0; mf < 8; ++mf)
#pragma unroll
    for (int r = 0; r < 4; ++r) {
      float bv = bp1[wm * 128 + mf * 16 + quad * 4 + r];
      acc2[mf][0][r] = bv; acc2[mf][1][r] = bv;
    }
#pragma unroll 1
  for (int kc = 0; kc < 8; ++kc) {
    f16x8 vw[4];
#pragma unroll
    for (int i = 0; i < 4; ++i)
      vw[i] = *(const f16x8*)&Wp2[(size_t)(sr + i * 64) * 256 + kc * 32 + ss * 8];
    __syncthreads();
#pragma unroll
    for (int i = 0; i < 4; ++i) *(f16x8*)&wsv[(sr + i * 64) * 40 + ss * 8] = vw[i];
    __syncthreads();
    f16x8 bf0 = *(const f16x8*)&pa[(wn * 32 + l15) * 264 + kc * 32 + quad * 8];
    f16x8 bf1 = *(const f16x8*)&pa[(wn * 32 + 16 + l15) * 264 + kc * 32 + quad * 8];
#pragma unroll
    for (int mf = 0; mf < 8; ++mf) {
      f16x8 af = *(const f16x8*)&wsv[(wm * 128 + mf * 16 + l15) * 40 + quad * 8];
      acc2[mf][0] = MFMA16(af, bf0, acc2[mf][0]);
      acc2[mf][1] = MFMA16(af, bf1, acc2[mf][1]);
    }
  }
#pragma unroll
  for (int mf = 0; mf < 8; ++mf)
#pragma unroll
    for (int nf = 0; nf < 2; ++nf) {
      int n = n0 + wn * 32 + nf * 16 + l15;
#pragma unroll
      for (int r = 0; r < 4; ++r) {
        int o = wm * 128 + mf * 16 + quad * 4 + r;
        out[((size_t)b * C + o) * HW + n] = acc2[mf][nf][r];
      }
    }
}

// ============================================================================
extern "C" void kernel_launch(void* const* d_in, const int* in_sizes, int n_in,
                              void* d_out, int out_size, void* d_ws, size_t ws_size,
                              hipStream_t stream) {
  (void)in_sizes; (void)n_in; (void)out_size; (void)ws_size;
  const float* input = (const float*)d_in[0];
  const float* Wq  = (const float*)d_in[2];
  const float* gq  = (const float*)d_in[3];
  const float* bq  = (const float*)d_in[4];
  const float* mq  = (const float*)d_in[5];
  const float* vq  = (const float*)d_in[6];
  const float* Wkv = (const float*)d_in[7];
  const float* gkv = (const float*)d_in[8];
  const float* bkv = (const float*)d_in[9];
  const float* mkv = (const float*)d_in[10];
  const float* vkv = (const float*)d_in[11];
  const float* Wp  = (const float*)d_in[12];
  const float* gp  = (const float*)d_in[13];
  const float* bp  = (const float*)d_in[14];
  const float* mp  = (const float*)d_in[15];
  const float* vp  = (const float*)d_in[16];

  char* ws = (char*)d_ws;
  f16*   XTw = (f16*)(ws + OFF_XT);
  float* kvw = (float*)(ws + OFF_KV);
  f16*   W1  = (f16*)(ws + OFF_W1);
  float* b1  = (float*)(ws + OFF_B1);
  f16*   Wp2 = (f16*)(ws + OFF_WP);
  float* bp2 = (float*)(ws + OFF_BP);
  float* rm  = (float*)(ws + OFF_RM);
  float* rs  = (float*)(ws + OFF_RS);
  float* U   = (float*)(ws + OFF_U);
  float* out = (float*)d_out;

  const f16* Wq2  = W1;            // rows 0..255
  const f16* Wkv2 = W1 + 65536;    // rows 256..287
  const float* bq1  = b1;
  const float* bkv1 = b1 + 256;

  hipMemsetAsync(U, 0, (size_t)BATCH * DH * DH * 4, stream);
  k0_prep<<<547, 256, 0, stream>>>(Wq, gq, bq, mq, vq, Wkv, gkv, bkv, mkv, vkv,
                                   Wp, gp, bp, mp, vp, W1, b1, Wp2, bp2);
  p0_trans_kv<<<dim3(64, 16), 256, 0, stream>>>(input, Wkv2, bkv1, XTw, kvw);
  k2_stats<<<512, 256, 0, stream>>>(kvw, rm, rs);
  k3_ctx<<<dim3(8, 16), 256, 0, stream>>>(kvw, rm, rs, U);
  kb_mega<<<dim3(64, 16), 256, 0, stream>>>(XTw, Wq2, bq1, U, Wp2, bp2, out);
}